// Round 4
// baseline (269.474 us; speedup 1.0000x reference)
//
#include <hip/hip_runtime.h>
#include <hip/hip_bf16.h>
#include <stdint.h>

#define DM 1024
#define NPAT 8
#define LDS_A 0
#define LDS_B 65536

typedef __bf16 bf16x8_t __attribute__((ext_vector_type(8)));
typedef float f32x4_t __attribute__((ext_vector_type(4)));
typedef unsigned short u16;

typedef const __attribute__((address_space(1))) void* gas_ptr;
typedef __attribute__((address_space(3))) void* las_ptr;

__device__ __forceinline__ u16 f2bf(float x) {
  uint32_t u = __float_as_uint(x);
  uint32_t r = (u + 0x7FFFu + ((u >> 16) & 1u)) >> 16;  // RNE
  return (u16)r;
}

// ---------------- K0: proj_w f32 -> bf16 ----------------
__global__ __launch_bounds__(256) void k0_cvt_w(const float* __restrict__ w,
                                                u16* __restrict__ wb) {
  int i = blockIdx.x * 256 + threadIdx.x;
  float4 v = ((const float4*)w)[i];
  ushort4 o;
  o.x = f2bf(v.x); o.y = f2bf(v.y); o.z = f2bf(v.z); o.w = f2bf(v.w);
  ((ushort4*)wb)[i] = o;
}

// ---------------- K1: hopfield read + residual + cast (unchanged) ----------
__global__ __launch_bounds__(256) void k1_hopfield(const float* __restrict__ h,
                                                   const float* __restrict__ pat,
                                                   u16* __restrict__ A, int M) {
  __shared__ float patL[NPAT * DM];
  const int tid = threadIdx.x;
  {
    const float4* p4 = (const float4*)pat;
    float4* l4 = (float4*)patL;
#pragma unroll
    for (int i = 0; i < (NPAT * DM / 4) / 256; ++i)
      l4[i * 256 + tid] = p4[i * 256 + tid];
  }
  __syncthreads();

  const int lane = tid & 63;
  const int wid = (blockIdx.x << 2) | (tid >> 6);
  const int nw = gridDim.x << 2;
  const float4* h4 = (const float4*)h;
  const float4* pl4 = (const float4*)patL;
  ushort4* A4 = (ushort4*)A;

  for (int rp = wid; rp < (M >> 1); rp += nw) {
    const size_t r0 = (size_t)rp << 1;
    float4 hv0[4], hv1[4];
#pragma unroll
    for (int j = 0; j < 4; ++j) {
      hv0[j] = h4[r0 * 256 + j * 64 + lane];
      hv1[j] = h4[(r0 + 1) * 256 + j * 64 + lane];
    }
    float d0[NPAT], d1[NPAT];
#pragma unroll
    for (int p = 0; p < NPAT; ++p) {
      float a = 0.f, b = 0.f;
#pragma unroll
      for (int j = 0; j < 4; ++j) {
        float4 pv = pl4[p * 256 + j * 64 + lane];
        a = fmaf(hv0[j].x, pv.x, a); a = fmaf(hv0[j].y, pv.y, a);
        a = fmaf(hv0[j].z, pv.z, a); a = fmaf(hv0[j].w, pv.w, a);
        b = fmaf(hv1[j].x, pv.x, b); b = fmaf(hv1[j].y, pv.y, b);
        b = fmaf(hv1[j].z, pv.z, b); b = fmaf(hv1[j].w, pv.w, b);
      }
      d0[p] = a; d1[p] = b;
    }
#pragma unroll
    for (int p = 0; p < NPAT; ++p) {
#pragma unroll
      for (int o = 32; o > 0; o >>= 1) {
        d0[p] += __shfl_xor(d0[p], o);
        d1[p] += __shfl_xor(d1[p], o);
      }
    }
    float m0 = d0[0], m1 = d1[0];
#pragma unroll
    for (int p = 1; p < NPAT; ++p) { m0 = fmaxf(m0, d0[p]); m1 = fmaxf(m1, d1[p]); }
    float s0 = 0.f, s1 = 0.f;
#pragma unroll
    for (int p = 0; p < NPAT; ++p) {
      d0[p] = __expf(d0[p] - m0); s0 += d0[p];
      d1[p] = __expf(d1[p] - m1); s1 += d1[p];
    }
    const float i0 = 1.f / s0, i1 = 1.f / s1;
#pragma unroll
    for (int p = 0; p < NPAT; ++p) { d0[p] *= i0; d1[p] *= i1; }

#pragma unroll
    for (int j = 0; j < 4; ++j) {
      float4 a0 = hv0[j], a1 = hv1[j];
#pragma unroll
      for (int p = 0; p < NPAT; ++p) {
        float4 pv = pl4[p * 256 + j * 64 + lane];
        a0.x = fmaf(d0[p], pv.x, a0.x); a0.y = fmaf(d0[p], pv.y, a0.y);
        a0.z = fmaf(d0[p], pv.z, a0.z); a0.w = fmaf(d0[p], pv.w, a0.w);
        a1.x = fmaf(d1[p], pv.x, a1.x); a1.y = fmaf(d1[p], pv.y, a1.y);
        a1.z = fmaf(d1[p], pv.z, a1.z); a1.w = fmaf(d1[p], pv.w, a1.w);
      }
      ushort4 o0, o1;
      o0.x = f2bf(a0.x); o0.y = f2bf(a0.y); o0.z = f2bf(a0.z); o0.w = f2bf(a0.w);
      o1.x = f2bf(a1.x); o1.y = f2bf(a1.y); o1.z = f2bf(a1.z); o1.w = f2bf(a1.w);
      A4[r0 * 256 + j * 64 + lane] = o0;
      A4[(r0 + 1) * 256 + j * 64 + lane] = o1;
    }
  }
}

// ---------------- K2: persistent 256x(4x256) 8-phase bf16 GEMM ---------------
// Each block: one A panel (tm), 4 sub-GEMMs g=0..3 (tn=g), single 64-tile
// pipelined loop u = g*16 + kt. BOTH A and B staged every tile (R3's
// stage-A-once was unsound: 2 LDS slots can't hold 16 K-slices). Schedule is
// byte-identical to the verified R2 template; only B's global base advances
// with g and interior epilogues ((u&15)==15) overlap the pipeline.
// vmcnt ledger (uniform 8 loads/tile): end-of-tile u<=61 -> vmcnt(4)
// (retires everything of tile u+1, leaves the 4 newest = tile u+2's lo
// halves); u==62 -> vmcnt(0) (nothing staged for u+2=64); u==63 -> none.
// Interior-epilogue stores enqueue after the tile-15/31/47 wait; the next
// tile-end vmcnt(4) over-drains them (safe).
#define STAGE(basePtr, regionOff, kt, hf, bufOff)                                        \
  do {                                                                                   \
    const u16* _s = (basePtr) + (size_t)((hf)*128) * DM + (kt)*64;                       \
    char* _d = lds + (regionOff) + (bufOff) + (hf)*16384;                                \
    __builtin_amdgcn_global_load_lds((gas_ptr)(_s + go0), (las_ptr)(_d + L0), 16, 0, 0); \
    __builtin_amdgcn_global_load_lds((gas_ptr)(_s + go1), (las_ptr)(_d + L1), 16, 0, 0); \
  } while (0)

#define RD(p) (*(const bf16x8_t*)(p))

__global__ __launch_bounds__(512, 2) void k2_gemm(const u16* __restrict__ A,
                                                  const u16* __restrict__ B,
                                                  const float* __restrict__ bias,
                                                  float* __restrict__ C, int M) {
  __shared__ __align__(16) char lds[131072];
  const int tid = threadIdx.x;
  const int lane = tid & 63;
  const int wave = tid >> 6;   // 0..7
  const int wm = wave >> 2;    // 0..1 -> A row-half
  const int wn = wave & 3;     // 0..3 -> B rows wn*64..+63
  const int r16 = lane & 15, kg = lane >> 4;

  const int tm = blockIdx.x;  // 256 blocks, 1 per CU; A panel block-private
  const u16* Ab = A + (size_t)tm * 256 * DM;

  // staging thread->source map (inverse of read swizzle; involution)
  const uint32_t L0 = (uint32_t)tid * 16;
  const uint32_t L1 = 8192u + (uint32_t)tid * 16;
  const uint32_t S0 = L0 ^ (((L0 >> 7) & 7u) << 4);
  const uint32_t S1 = L1 ^ (((L1 >> 7) & 7u) << 4);
  const uint32_t go0 = (S0 >> 7) * DM + ((S0 & 127u) >> 1);
  const uint32_t go1 = (S1 >> 7) * DM + ((S1 & 127u) >> 1);

  // ds_read swizzled offsets
  const uint32_t flip = (uint32_t)(r16 & 7) << 4;
  const uint32_t aoff0 = ((uint32_t)(r16 * 128 + kg * 16)) ^ flip;
  const uint32_t aoff1 = ((uint32_t)(r16 * 128 + 64 + kg * 16)) ^ flip;
  const uint32_t brow = (uint32_t)((wn & 1) * 64 + r16);
  const uint32_t boff0 = ((uint32_t)(brow * 128 + kg * 16)) ^ flip;
  const uint32_t boff1 = ((uint32_t)(brow * 128 + 64 + kg * 16)) ^ flip;
  const uint32_t aHalfSel = (uint32_t)wm * 16384;
  const uint32_t bHalfSel = (uint32_t)(wn >> 1) * 16384;

  const int rowB = tm * 256 + wm * 128 + kg * 4;

  f32x4_t acc[8][4] = {};
  bf16x8_t aq[4][2], bl[2][2], bh[2][2];

  // prologue (g=0): Blo0,Alo0,Bhi0,Ahi0,Blo1,Alo1; vmcnt(4) leaves Blo1+Alo1
  STAGE(B, LDS_B, 0, 0, 0);
  STAGE(Ab, LDS_A, 0, 0, 0);
  STAGE(B, LDS_B, 0, 1, 0);
  STAGE(Ab, LDS_A, 0, 1, 0);
  STAGE(B, LDS_B, 1, 0, 32768);
  STAGE(Ab, LDS_A, 1, 0, 32768);
  asm volatile("s_waitcnt vmcnt(4)");
  __builtin_amdgcn_s_barrier();

#pragma unroll 2
  for (int u = 0; u < 64; ++u) {
    const uint32_t co = (uint32_t)(u & 1) << 15;
    const uint32_t no = co ^ 32768u;
    const char* a0 = lds + LDS_A + co + aHalfSel + aoff0;
    const char* a1 = lds + LDS_A + co + aHalfSel + aoff1;
    const char* b0 = lds + LDS_B + co + bHalfSel + boff0;
    const char* b1 = lds + LDS_B + co + bHalfSel + boff1;

    // ---- phase 0: rd A m0-3 + B n0-1 ; stage Bhi(u+1) ----
#pragma unroll
    for (int m = 0; m < 4; ++m) { aq[m][0] = RD(a0 + m * 2048); aq[m][1] = RD(a1 + m * 2048); }
#pragma unroll
    for (int n = 0; n < 2; ++n) { bl[n][0] = RD(b0 + n * 2048); bl[n][1] = RD(b1 + n * 2048); }
    if (u + 1 < 64) STAGE(B + (size_t)((u + 1) >> 4) * 256 * DM, LDS_B, (u + 1) & 15, 1, no);
    __builtin_amdgcn_s_barrier();
    asm volatile("s_waitcnt lgkmcnt(0)");
    __builtin_amdgcn_s_setprio(1);
#pragma unroll
    for (int m = 0; m < 4; ++m)
#pragma unroll
      for (int n = 0; n < 2; ++n)
#pragma unroll
        for (int ks = 0; ks < 2; ++ks)
          acc[m][n] = __builtin_amdgcn_mfma_f32_16x16x32_bf16(aq[m][ks], bl[n][ks], acc[m][n], 0, 0, 0);
    __builtin_amdgcn_s_setprio(0);
    __builtin_amdgcn_s_barrier();

    // ---- phase 1: rd B n2-3 ; stage Ahi(u+1) ----
#pragma unroll
    for (int n = 0; n < 2; ++n) { bh[n][0] = RD(b0 + (n + 2) * 2048); bh[n][1] = RD(b1 + (n + 2) * 2048); }
    if (u + 1 < 64) STAGE(Ab, LDS_A, (u + 1) & 15, 1, no);
    __builtin_amdgcn_s_barrier();
    asm volatile("s_waitcnt lgkmcnt(0)");
    __builtin_amdgcn_s_setprio(1);
#pragma unroll
    for (int m = 0; m < 4; ++m)
#pragma unroll
      for (int n = 0; n < 2; ++n)
#pragma unroll
        for (int ks = 0; ks < 2; ++ks)
          acc[m][n + 2] = __builtin_amdgcn_mfma_f32_16x16x32_bf16(aq[m][ks], bh[n][ks], acc[m][n + 2], 0, 0, 0);
    __builtin_amdgcn_s_setprio(0);
    __builtin_amdgcn_s_barrier();

    // ---- phase 2: rd A m4-7 ; stage Blo(u+2) ----
#pragma unroll
    for (int m = 0; m < 4; ++m) { aq[m][0] = RD(a0 + (m + 4) * 2048); aq[m][1] = RD(a1 + (m + 4) * 2048); }
    if (u + 2 < 64) STAGE(B + (size_t)((u + 2) >> 4) * 256 * DM, LDS_B, (u + 2) & 15, 0, co);
    __builtin_amdgcn_s_barrier();
    asm volatile("s_waitcnt lgkmcnt(0)");
    __builtin_amdgcn_s_setprio(1);
#pragma unroll
    for (int m = 0; m < 4; ++m)
#pragma unroll
      for (int n = 0; n < 2; ++n)
#pragma unroll
        for (int ks = 0; ks < 2; ++ks)
          acc[m + 4][n] = __builtin_amdgcn_mfma_f32_16x16x32_bf16(aq[m][ks], bl[n][ks], acc[m + 4][n], 0, 0, 0);
    __builtin_amdgcn_s_setprio(0);
    __builtin_amdgcn_s_barrier();

    // ---- phase 3: stage Alo(u+2) ; tile-end counted wait ----
    if (u + 2 < 64) STAGE(Ab, LDS_A, (u + 2) & 15, 0, co);
    __builtin_amdgcn_s_barrier();
    __builtin_amdgcn_s_setprio(1);
#pragma unroll
    for (int m = 0; m < 4; ++m)
#pragma unroll
      for (int n = 0; n < 2; ++n)
#pragma unroll
        for (int ks = 0; ks < 2; ++ks)
          acc[m + 4][n + 2] = __builtin_amdgcn_mfma_f32_16x16x32_bf16(aq[m][ks], bh[n][ks], acc[m + 4][n + 2], 0, 0, 0);
    __builtin_amdgcn_s_setprio(0);
    if (u <= 61)      asm volatile("s_waitcnt vmcnt(4)");
    else if (u == 62) asm volatile("s_waitcnt vmcnt(0)");
    __builtin_amdgcn_s_barrier();

    // ---- interior/final epilogue: write C for sub-GEMM g, reset acc ----
    if ((u & 15) == 15) {
      const int g = u >> 4;
      const int colB = g * 256 + wn * 64 + r16;
      float bvv[4];
#pragma unroll
      for (int n = 0; n < 4; ++n) bvv[n] = bias[colB + n * 16];
#pragma unroll
      for (int m = 0; m < 8; ++m) {
#pragma unroll
        for (int r = 0; r < 4; ++r) {
          float* cp = C + (size_t)(rowB + m * 16 + r) * DM + colB;
#pragma unroll
          for (int n = 0; n < 4; ++n) cp[n * 16] = acc[m][n][r] + bvv[n];
        }
      }
#pragma unroll
      for (int m = 0; m < 8; ++m)
#pragma unroll
        for (int n = 0; n < 4; ++n)
#pragma unroll
          for (int r = 0; r < 4; ++r) acc[m][n][r] = 0.f;
    }
  }
}

extern "C" void kernel_launch(void* const* d_in, const int* in_sizes, int n_in,
                              void* d_out, int out_size, void* d_ws, size_t ws_size,
                              hipStream_t stream) {
  const float* h = (const float*)d_in[0];
  const float* pat = (const float*)d_in[1];
  const float* w = (const float*)d_in[2];
  const float* b = (const float*)d_in[3];
  float* out = (float*)d_out;
  const int M = in_sizes[0] / DM;  // 65536

  u16* Wb = (u16*)d_ws;                     // 2 MiB
  u16* Abf = (u16*)d_ws + (size_t)DM * DM;  // 128 MiB

  k0_cvt_w<<<DM * DM / 4 / 256, 256, 0, stream>>>(w, Wb);
  k1_hopfield<<<2048, 256, 0, stream>>>(h, pat, Abf, M);
  k2_gemm<<<M / 256, 512, 0, stream>>>(Abf, Wb, b, out, M);
}

// Round 6
// 241.317 us; speedup vs baseline: 1.1167x; 1.1167x over previous
//
#include <hip/hip_runtime.h>
#include <hip/hip_bf16.h>
#include <stdint.h>

#define DM 1024
#define NPAT 8
#define NKT 16  // K-tiles of 64: 1024/64
#define LDS_A 0
#define LDS_B 65536

typedef __bf16 bf16x8_t __attribute__((ext_vector_type(8)));
typedef float f32x4_t __attribute__((ext_vector_type(4)));
typedef unsigned short u16;

typedef const __attribute__((address_space(1))) void* gas_ptr;
typedef __attribute__((address_space(3))) void* las_ptr;

__device__ __forceinline__ u16 f2bf(float x) {
  uint32_t u = __float_as_uint(x);
  uint32_t r = (u + 0x7FFFu + ((u >> 16) & 1u)) >> 16;  // RNE
  return (u16)r;
}

// ---------------- K0: proj_w f32 -> bf16 ----------------
__global__ __launch_bounds__(256) void k0_cvt_w(const float* __restrict__ w,
                                                u16* __restrict__ wb) {
  int i = blockIdx.x * 256 + threadIdx.x;
  float4 v = ((const float4*)w)[i];
  ushort4 o;
  o.x = f2bf(v.x); o.y = f2bf(v.y); o.z = f2bf(v.z); o.w = f2bf(v.w);
  ((ushort4*)wb)[i] = o;
}

// ---------------- K1: hopfield read + residual + cast ----------------
// nt-loads on h (read-once stream, via ext_vector_type — HIP float4 is not
// accepted by the builtin): keep L2/L3 capacity for the Abf writes that K2
// re-reads. Abf stores stay temporal (K2 wants them cached).
__global__ __launch_bounds__(256) void k1_hopfield(const float* __restrict__ h,
                                                   const float* __restrict__ pat,
                                                   u16* __restrict__ A, int M) {
  __shared__ float patL[NPAT * DM];
  const int tid = threadIdx.x;
  {
    const float4* p4 = (const float4*)pat;
    float4* l4 = (float4*)patL;
#pragma unroll
    for (int i = 0; i < (NPAT * DM / 4) / 256; ++i)
      l4[i * 256 + tid] = p4[i * 256 + tid];
  }
  __syncthreads();

  const int lane = tid & 63;
  const int wid = (blockIdx.x << 2) | (tid >> 6);
  const int nw = gridDim.x << 2;
  const f32x4_t* h4 = (const f32x4_t*)h;
  const f32x4_t* pl4 = (const f32x4_t*)patL;
  ushort4* A4 = (ushort4*)A;

  for (int rp = wid; rp < (M >> 1); rp += nw) {
    const size_t r0 = (size_t)rp << 1;
    f32x4_t hv0[4], hv1[4];
#pragma unroll
    for (int j = 0; j < 4; ++j) {
      hv0[j] = __builtin_nontemporal_load(&h4[r0 * 256 + j * 64 + lane]);
      hv1[j] = __builtin_nontemporal_load(&h4[(r0 + 1) * 256 + j * 64 + lane]);
    }
    float d0[NPAT], d1[NPAT];
#pragma unroll
    for (int p = 0; p < NPAT; ++p) {
      float a = 0.f, b = 0.f;
#pragma unroll
      for (int j = 0; j < 4; ++j) {
        f32x4_t pv = pl4[p * 256 + j * 64 + lane];
#pragma unroll
        for (int e = 0; e < 4; ++e) {
          a = fmaf(hv0[j][e], pv[e], a);
          b = fmaf(hv1[j][e], pv[e], b);
        }
      }
      d0[p] = a; d1[p] = b;
    }
#pragma unroll
    for (int p = 0; p < NPAT; ++p) {
#pragma unroll
      for (int o = 32; o > 0; o >>= 1) {
        d0[p] += __shfl_xor(d0[p], o);
        d1[p] += __shfl_xor(d1[p], o);
      }
    }
    float m0 = d0[0], m1 = d1[0];
#pragma unroll
    for (int p = 1; p < NPAT; ++p) { m0 = fmaxf(m0, d0[p]); m1 = fmaxf(m1, d1[p]); }
    float s0 = 0.f, s1 = 0.f;
#pragma unroll
    for (int p = 0; p < NPAT; ++p) {
      d0[p] = __expf(d0[p] - m0); s0 += d0[p];
      d1[p] = __expf(d1[p] - m1); s1 += d1[p];
    }
    const float i0 = 1.f / s0, i1 = 1.f / s1;
#pragma unroll
    for (int p = 0; p < NPAT; ++p) { d0[p] *= i0; d1[p] *= i1; }

#pragma unroll
    for (int j = 0; j < 4; ++j) {
      f32x4_t a0 = hv0[j], a1 = hv1[j];
#pragma unroll
      for (int p = 0; p < NPAT; ++p) {
        f32x4_t pv = pl4[p * 256 + j * 64 + lane];
#pragma unroll
        for (int e = 0; e < 4; ++e) {
          a0[e] = fmaf(d0[p], pv[e], a0[e]);
          a1[e] = fmaf(d1[p], pv[e], a1[e]);
        }
      }
      ushort4 o0, o1;
      o0.x = f2bf(a0[0]); o0.y = f2bf(a0[1]); o0.z = f2bf(a0[2]); o0.w = f2bf(a0[3]);
      o1.x = f2bf(a1[0]); o1.y = f2bf(a1[1]); o1.z = f2bf(a1[2]); o1.w = f2bf(a1[3]);
      A4[r0 * 256 + j * 64 + lane] = o0;
      A4[(r0 + 1) * 256 + j * 64 + lane] = o1;
    }
  }
}

// ---------------- K2: 256x256 8-phase bf16 GEMM (verified R2 structure) -----
// 1024 blocks (tm x tn), XCD-bijective swizzle, single terminal epilogue with
// NON-TEMPORAL C stores (C is write-once; keep it out of L2/L3 so A panels
// and Abf stay resident for the cross-block refetch).
#define STAGE(matBase, regionOff, kt, hf, bufOff)                                        \
  do {                                                                                   \
    const u16* _s = (matBase) + (size_t)((hf)*128) * DM + (kt)*64;                       \
    char* _d = lds + (regionOff) + (bufOff) + (hf)*16384;                                \
    __builtin_amdgcn_global_load_lds((gas_ptr)(_s + go0), (las_ptr)(_d + L0), 16, 0, 0); \
    __builtin_amdgcn_global_load_lds((gas_ptr)(_s + go1), (las_ptr)(_d + L1), 16, 0, 0); \
  } while (0)

#define RD(p) (*(const bf16x8_t*)(p))

__global__ __launch_bounds__(512, 2) void k2_gemm(const u16* __restrict__ A,
                                                  const u16* __restrict__ B,
                                                  const float* __restrict__ bias,
                                                  float* __restrict__ C, int M) {
  __shared__ __align__(16) char lds[131072];
  const int tid = threadIdx.x;
  const int lane = tid & 63;
  const int wave = tid >> 6;   // 0..7
  const int wm = wave >> 2;    // 0..1 -> A half
  const int wn = wave & 3;     // 0..3 -> B rows wn*64..+63
  const int r16 = lane & 15, kg = lane >> 4;

  // XCD-bijective swizzle: 1024 % 8 == 0; 4 consecutive intra-XCD ids share
  // one A panel (tm).
  const int bid = blockIdx.x;
  const int swz = (bid & 7) * 128 + (bid >> 3);
  const int tn = swz & 3, tm = swz >> 2;

  const u16* Ab = A + (size_t)tm * 256 * DM;
  const u16* Bb = B + (size_t)tn * 256 * DM;

  // staging thread->source map (inverse of read swizzle; involution)
  const uint32_t L0 = (uint32_t)tid * 16;
  const uint32_t L1 = 8192u + (uint32_t)tid * 16;
  const uint32_t S0 = L0 ^ (((L0 >> 7) & 7u) << 4);
  const uint32_t S1 = L1 ^ (((L1 >> 7) & 7u) << 4);
  const uint32_t go0 = (S0 >> 7) * DM + ((S0 & 127u) >> 1);
  const uint32_t go1 = (S1 >> 7) * DM + ((S1 & 127u) >> 1);

  // ds_read swizzled offsets
  const uint32_t flip = (uint32_t)(r16 & 7) << 4;
  const uint32_t aoff0 = ((uint32_t)(r16 * 128 + kg * 16)) ^ flip;
  const uint32_t aoff1 = ((uint32_t)(r16 * 128 + 64 + kg * 16)) ^ flip;
  const uint32_t brow = (uint32_t)((wn & 1) * 64 + r16);
  const uint32_t boff0 = ((uint32_t)(brow * 128 + kg * 16)) ^ flip;
  const uint32_t boff1 = ((uint32_t)(brow * 128 + 64 + kg * 16)) ^ flip;
  const uint32_t aHalfSel = (uint32_t)wm * 16384;
  const uint32_t bHalfSel = (uint32_t)(wn >> 1) * 16384;

  f32x4_t acc[8][4] = {};
  bf16x8_t aq[4][2], bl[2][2], bh[2][2];

  // prologue: Blo0,Alo0,Bhi0,Ahi0,Blo1,Alo1; vmcnt(4) leaves Blo1+Alo1
  STAGE(Bb, LDS_B, 0, 0, 0);
  STAGE(Ab, LDS_A, 0, 0, 0);
  STAGE(Bb, LDS_B, 0, 1, 0);
  STAGE(Ab, LDS_A, 0, 1, 0);
  STAGE(Bb, LDS_B, 1, 0, 32768);
  STAGE(Ab, LDS_A, 1, 0, 32768);
  asm volatile("s_waitcnt vmcnt(4)");
  __builtin_amdgcn_s_barrier();

  for (int t = 0; t < NKT; ++t) {
    const uint32_t co = (uint32_t)(t & 1) << 15;
    const uint32_t no = co ^ 32768u;
    const char* a0 = lds + LDS_A + co + aHalfSel + aoff0;
    const char* a1 = lds + LDS_A + co + aHalfSel + aoff1;
    const char* b0 = lds + LDS_B + co + bHalfSel + boff0;
    const char* b1 = lds + LDS_B + co + bHalfSel + boff1;

    // ---- phase 0: A m0-3, B n0-1 ; stage Bhi(t+1) ----
#pragma unroll
    for (int m = 0; m < 4; ++m) { aq[m][0] = RD(a0 + m * 2048); aq[m][1] = RD(a1 + m * 2048); }
#pragma unroll
    for (int n = 0; n < 2; ++n) { bl[n][0] = RD(b0 + n * 2048); bl[n][1] = RD(b1 + n * 2048); }
    if (t + 1 < NKT) STAGE(Bb, LDS_B, t + 1, 1, no);
    __builtin_amdgcn_s_barrier();
    asm volatile("s_waitcnt lgkmcnt(0)");
    __builtin_amdgcn_s_setprio(1);
#pragma unroll
    for (int m = 0; m < 4; ++m)
#pragma unroll
      for (int n = 0; n < 2; ++n)
#pragma unroll
        for (int ks = 0; ks < 2; ++ks)
          acc[m][n] = __builtin_amdgcn_mfma_f32_16x16x32_bf16(aq[m][ks], bl[n][ks], acc[m][n], 0, 0, 0);
    __builtin_amdgcn_s_setprio(0);
    __builtin_amdgcn_s_barrier();

    // ---- phase 1: B n2-3 ; stage Ahi(t+1) ----
#pragma unroll
    for (int n = 0; n < 2; ++n) { bh[n][0] = RD(b0 + (n + 2) * 2048); bh[n][1] = RD(b1 + (n + 2) * 2048); }
    if (t + 1 < NKT) STAGE(Ab, LDS_A, t + 1, 1, no);
    __builtin_amdgcn_s_barrier();
    asm volatile("s_waitcnt lgkmcnt(0)");
    __builtin_amdgcn_s_setprio(1);
#pragma unroll
    for (int m = 0; m < 4; ++m)
#pragma unroll
      for (int n = 0; n < 2; ++n)
#pragma unroll
        for (int ks = 0; ks < 2; ++ks)
          acc[m][n + 2] = __builtin_amdgcn_mfma_f32_16x16x32_bf16(aq[m][ks], bh[n][ks], acc[m][n + 2], 0, 0, 0);
    __builtin_amdgcn_s_setprio(0);
    __builtin_amdgcn_s_barrier();

    // ---- phase 2: A m4-7 ; stage Blo(t+2) ----
#pragma unroll
    for (int m = 0; m < 4; ++m) { aq[m][0] = RD(a0 + (m + 4) * 2048); aq[m][1] = RD(a1 + (m + 4) * 2048); }
    if (t + 2 < NKT) STAGE(Bb, LDS_B, t + 2, 0, co);
    __builtin_amdgcn_s_barrier();
    asm volatile("s_waitcnt lgkmcnt(0)");
    __builtin_amdgcn_s_setprio(1);
#pragma unroll
    for (int m = 0; m < 4; ++m)
#pragma unroll
      for (int n = 0; n < 2; ++n)
#pragma unroll
        for (int ks = 0; ks < 2; ++ks)
          acc[m + 4][n] = __builtin_amdgcn_mfma_f32_16x16x32_bf16(aq[m][ks], bl[n][ks], acc[m + 4][n], 0, 0, 0);
    __builtin_amdgcn_s_setprio(0);
    __builtin_amdgcn_s_barrier();

    // ---- phase 3: stage Alo(t+2) ; tile-end counted wait ----
    if (t + 2 < NKT) STAGE(Ab, LDS_A, t + 2, 0, co);
    __builtin_amdgcn_s_barrier();
    __builtin_amdgcn_s_setprio(1);
#pragma unroll
    for (int m = 0; m < 4; ++m)
#pragma unroll
      for (int n = 0; n < 2; ++n)
#pragma unroll
        for (int ks = 0; ks < 2; ++ks)
          acc[m + 4][n + 2] = __builtin_amdgcn_mfma_f32_16x16x32_bf16(aq[m][ks], bh[n][ks], acc[m + 4][n + 2], 0, 0, 0);
    __builtin_amdgcn_s_setprio(0);
    if (t < NKT - 1) {
      if (t + 2 < NKT) asm volatile("s_waitcnt vmcnt(4)");
      else             asm volatile("s_waitcnt vmcnt(0)");
    }
    __builtin_amdgcn_s_barrier();
  }

  // epilogue: C/D layout col=lane&15, row=(lane>>4)*4+reg; nt stores
  const int colB = tn * 256 + wn * 64 + r16;
  const int rowB = tm * 256 + wm * 128 + kg * 4;
  float bvv[4];
#pragma unroll
  for (int n = 0; n < 4; ++n) bvv[n] = bias[colB + n * 16];
#pragma unroll
  for (int m = 0; m < 8; ++m) {
#pragma unroll
    for (int r = 0; r < 4; ++r) {
      float* cp = C + (size_t)(rowB + m * 16 + r) * DM + colB;
#pragma unroll
      for (int n = 0; n < 4; ++n)
        __builtin_nontemporal_store(acc[m][n][r] + bvv[n], &cp[n * 16]);
    }
  }
}

extern "C" void kernel_launch(void* const* d_in, const int* in_sizes, int n_in,
                              void* d_out, int out_size, void* d_ws, size_t ws_size,
                              hipStream_t stream) {
  const float* h = (const float*)d_in[0];
  const float* pat = (const float*)d_in[1];
  const float* w = (const float*)d_in[2];
  const float* b = (const float*)d_in[3];
  float* out = (float*)d_out;
  const int M = in_sizes[0] / DM;  // 65536

  u16* Wb = (u16*)d_ws;                     // 2 MiB
  u16* Abf = (u16*)d_ws + (size_t)DM * DM;  // 128 MiB

  k0_cvt_w<<<DM * DM / 4 / 256, 256, 0, stream>>>(w, Wb);
  k1_hopfield<<<2048, 256, 0, stream>>>(h, pat, Abf, M);
  k2_gemm<<<(M / 256) * (DM / 256), 512, 0, stream>>>(Abf, Wb, b, out, M);
}

// Round 7
// 230.218 us; speedup vs baseline: 1.1705x; 1.0482x over previous
//
#include <hip/hip_runtime.h>
#include <hip/hip_bf16.h>
#include <stdint.h>

#define DM 1024
#define NPAT 8
#define NKT 16  // K-tiles of 64: 1024/64
#define LDS_A 0
#define LDS_B 65536

typedef __bf16 bf16x8_t __attribute__((ext_vector_type(8)));
typedef float f32x4_t __attribute__((ext_vector_type(4)));
typedef unsigned short u16;

typedef const __attribute__((address_space(1))) void* gas_ptr;
typedef __attribute__((address_space(3))) void* las_ptr;

__device__ __forceinline__ u16 f2bf(float x) {
  uint32_t u = __float_as_uint(x);
  uint32_t r = (u + 0x7FFFu + ((u >> 16) & 1u)) >> 16;  // RNE
  return (u16)r;
}

// ---------------- K0: proj_w f32 -> bf16 ----------------
__global__ __launch_bounds__(256) void k0_cvt_w(const float* __restrict__ w,
                                                u16* __restrict__ wb) {
  int i = blockIdx.x * 256 + threadIdx.x;
  float4 v = ((const float4*)w)[i];
  ushort4 o;
  o.x = f2bf(v.x); o.y = f2bf(v.y); o.z = f2bf(v.z); o.w = f2bf(v.w);
  ((ushort4*)wb)[i] = o;
}

// ---------------- K1: hopfield read + residual + cast ----------------
// nt-loads on h (read-once stream): avoids L2/L3 write-allocate pollution.
// Verified win in R6 (~25us). Abf stores stay temporal (K2 re-reads them).
__global__ __launch_bounds__(256) void k1_hopfield(const float* __restrict__ h,
                                                   const float* __restrict__ pat,
                                                   u16* __restrict__ A, int M) {
  __shared__ float patL[NPAT * DM];
  const int tid = threadIdx.x;
  {
    const float4* p4 = (const float4*)pat;
    float4* l4 = (float4*)patL;
#pragma unroll
    for (int i = 0; i < (NPAT * DM / 4) / 256; ++i)
      l4[i * 256 + tid] = p4[i * 256 + tid];
  }
  __syncthreads();

  const int lane = tid & 63;
  const int wid = (blockIdx.x << 2) | (tid >> 6);
  const int nw = gridDim.x << 2;
  const f32x4_t* h4 = (const f32x4_t*)h;
  const f32x4_t* pl4 = (const f32x4_t*)patL;
  ushort4* A4 = (ushort4*)A;

  for (int rp = wid; rp < (M >> 1); rp += nw) {
    const size_t r0 = (size_t)rp << 1;
    f32x4_t hv0[4], hv1[4];
#pragma unroll
    for (int j = 0; j < 4; ++j) {
      hv0[j] = __builtin_nontemporal_load(&h4[r0 * 256 + j * 64 + lane]);
      hv1[j] = __builtin_nontemporal_load(&h4[(r0 + 1) * 256 + j * 64 + lane]);
    }
    float d0[NPAT], d1[NPAT];
#pragma unroll
    for (int p = 0; p < NPAT; ++p) {
      float a = 0.f, b = 0.f;
#pragma unroll
      for (int j = 0; j < 4; ++j) {
        f32x4_t pv = pl4[p * 256 + j * 64 + lane];
#pragma unroll
        for (int e = 0; e < 4; ++e) {
          a = fmaf(hv0[j][e], pv[e], a);
          b = fmaf(hv1[j][e], pv[e], b);
        }
      }
      d0[p] = a; d1[p] = b;
    }
#pragma unroll
    for (int p = 0; p < NPAT; ++p) {
#pragma unroll
      for (int o = 32; o > 0; o >>= 1) {
        d0[p] += __shfl_xor(d0[p], o);
        d1[p] += __shfl_xor(d1[p], o);
      }
    }
    float m0 = d0[0], m1 = d1[0];
#pragma unroll
    for (int p = 1; p < NPAT; ++p) { m0 = fmaxf(m0, d0[p]); m1 = fmaxf(m1, d1[p]); }
    float s0 = 0.f, s1 = 0.f;
#pragma unroll
    for (int p = 0; p < NPAT; ++p) {
      d0[p] = __expf(d0[p] - m0); s0 += d0[p];
      d1[p] = __expf(d1[p] - m1); s1 += d1[p];
    }
    const float i0 = 1.f / s0, i1 = 1.f / s1;
#pragma unroll
    for (int p = 0; p < NPAT; ++p) { d0[p] *= i0; d1[p] *= i1; }

#pragma unroll
    for (int j = 0; j < 4; ++j) {
      f32x4_t a0 = hv0[j], a1 = hv1[j];
#pragma unroll
      for (int p = 0; p < NPAT; ++p) {
        f32x4_t pv = pl4[p * 256 + j * 64 + lane];
#pragma unroll
        for (int e = 0; e < 4; ++e) {
          a0[e] = fmaf(d0[p], pv[e], a0[e]);
          a1[e] = fmaf(d1[p], pv[e], a1[e]);
        }
      }
      ushort4 o0, o1;
      o0.x = f2bf(a0[0]); o0.y = f2bf(a0[1]); o0.z = f2bf(a0[2]); o0.w = f2bf(a0[3]);
      o1.x = f2bf(a1[0]); o1.y = f2bf(a1[1]); o1.z = f2bf(a1[2]); o1.w = f2bf(a1[3]);
      A4[r0 * 256 + j * 64 + lane] = o0;
      A4[(r0 + 1) * 256 + j * 64 + lane] = o1;
    }
  }
}

// ---------------- K2: 256x256 8-phase bf16 GEMM (verified R2 structure) -----
// 1024 blocks (tm x tn), XCD-bijective swizzle, single terminal epilogue with
// TEMPORAL C stores (R6 showed nt scattered stores cause partial-line RMW:
// WRITE +23%, dur +14us — reverted).
#define STAGE(matBase, regionOff, kt, hf, bufOff)                                        \
  do {                                                                                   \
    const u16* _s = (matBase) + (size_t)((hf)*128) * DM + (kt)*64;                       \
    char* _d = lds + (regionOff) + (bufOff) + (hf)*16384;                                \
    __builtin_amdgcn_global_load_lds((gas_ptr)(_s + go0), (las_ptr)(_d + L0), 16, 0, 0); \
    __builtin_amdgcn_global_load_lds((gas_ptr)(_s + go1), (las_ptr)(_d + L1), 16, 0, 0); \
  } while (0)

#define RD(p) (*(const bf16x8_t*)(p))

__global__ __launch_bounds__(512, 2) void k2_gemm(const u16* __restrict__ A,
                                                  const u16* __restrict__ B,
                                                  const float* __restrict__ bias,
                                                  float* __restrict__ C, int M) {
  __shared__ __align__(16) char lds[131072];
  const int tid = threadIdx.x;
  const int lane = tid & 63;
  const int wave = tid >> 6;   // 0..7
  const int wm = wave >> 2;    // 0..1 -> A half
  const int wn = wave & 3;     // 0..3 -> B rows wn*64..+63
  const int r16 = lane & 15, kg = lane >> 4;

  // XCD-bijective swizzle: 1024 % 8 == 0; 4 consecutive intra-XCD ids share
  // one A panel (tm).
  const int bid = blockIdx.x;
  const int swz = (bid & 7) * 128 + (bid >> 3);
  const int tn = swz & 3, tm = swz >> 2;

  const u16* Ab = A + (size_t)tm * 256 * DM;
  const u16* Bb = B + (size_t)tn * 256 * DM;

  // staging thread->source map (inverse of read swizzle; involution)
  const uint32_t L0 = (uint32_t)tid * 16;
  const uint32_t L1 = 8192u + (uint32_t)tid * 16;
  const uint32_t S0 = L0 ^ (((L0 >> 7) & 7u) << 4);
  const uint32_t S1 = L1 ^ (((L1 >> 7) & 7u) << 4);
  const uint32_t go0 = (S0 >> 7) * DM + ((S0 & 127u) >> 1);
  const uint32_t go1 = (S1 >> 7) * DM + ((S1 & 127u) >> 1);

  // ds_read swizzled offsets
  const uint32_t flip = (uint32_t)(r16 & 7) << 4;
  const uint32_t aoff0 = ((uint32_t)(r16 * 128 + kg * 16)) ^ flip;
  const uint32_t aoff1 = ((uint32_t)(r16 * 128 + 64 + kg * 16)) ^ flip;
  const uint32_t brow = (uint32_t)((wn & 1) * 64 + r16);
  const uint32_t boff0 = ((uint32_t)(brow * 128 + kg * 16)) ^ flip;
  const uint32_t boff1 = ((uint32_t)(brow * 128 + 64 + kg * 16)) ^ flip;
  const uint32_t aHalfSel = (uint32_t)wm * 16384;
  const uint32_t bHalfSel = (uint32_t)(wn >> 1) * 16384;

  f32x4_t acc[8][4] = {};
  bf16x8_t aq[4][2], bl[2][2], bh[2][2];

  // prologue: Blo0,Alo0,Bhi0,Ahi0,Blo1,Alo1; vmcnt(4) leaves Blo1+Alo1
  STAGE(Bb, LDS_B, 0, 0, 0);
  STAGE(Ab, LDS_A, 0, 0, 0);
  STAGE(Bb, LDS_B, 0, 1, 0);
  STAGE(Ab, LDS_A, 0, 1, 0);
  STAGE(Bb, LDS_B, 1, 0, 32768);
  STAGE(Ab, LDS_A, 1, 0, 32768);
  asm volatile("s_waitcnt vmcnt(4)");
  __builtin_amdgcn_s_barrier();

  for (int t = 0; t < NKT; ++t) {
    const uint32_t co = (uint32_t)(t & 1) << 15;
    const uint32_t no = co ^ 32768u;
    const char* a0 = lds + LDS_A + co + aHalfSel + aoff0;
    const char* a1 = lds + LDS_A + co + aHalfSel + aoff1;
    const char* b0 = lds + LDS_B + co + bHalfSel + boff0;
    const char* b1 = lds + LDS_B + co + bHalfSel + boff1;

    // ---- phase 0: A m0-3, B n0-1 ; stage Bhi(t+1) ----
#pragma unroll
    for (int m = 0; m < 4; ++m) { aq[m][0] = RD(a0 + m * 2048); aq[m][1] = RD(a1 + m * 2048); }
#pragma unroll
    for (int n = 0; n < 2; ++n) { bl[n][0] = RD(b0 + n * 2048); bl[n][1] = RD(b1 + n * 2048); }
    if (t + 1 < NKT) STAGE(Bb, LDS_B, t + 1, 1, no);
    __builtin_amdgcn_s_barrier();
    asm volatile("s_waitcnt lgkmcnt(0)");
    __builtin_amdgcn_s_setprio(1);
#pragma unroll
    for (int m = 0; m < 4; ++m)
#pragma unroll
      for (int n = 0; n < 2; ++n)
#pragma unroll
        for (int ks = 0; ks < 2; ++ks)
          acc[m][n] = __builtin_amdgcn_mfma_f32_16x16x32_bf16(aq[m][ks], bl[n][ks], acc[m][n], 0, 0, 0);
    __builtin_amdgcn_s_setprio(0);
    __builtin_amdgcn_s_barrier();

    // ---- phase 1: B n2-3 ; stage Ahi(t+1) ----
#pragma unroll
    for (int n = 0; n < 2; ++n) { bh[n][0] = RD(b0 + (n + 2) * 2048); bh[n][1] = RD(b1 + (n + 2) * 2048); }
    if (t + 1 < NKT) STAGE(Ab, LDS_A, t + 1, 1, no);
    __builtin_amdgcn_s_barrier();
    asm volatile("s_waitcnt lgkmcnt(0)");
    __builtin_amdgcn_s_setprio(1);
#pragma unroll
    for (int m = 0; m < 4; ++m)
#pragma unroll
      for (int n = 0; n < 2; ++n)
#pragma unroll
        for (int ks = 0; ks < 2; ++ks)
          acc[m][n + 2] = __builtin_amdgcn_mfma_f32_16x16x32_bf16(aq[m][ks], bh[n][ks], acc[m][n + 2], 0, 0, 0);
    __builtin_amdgcn_s_setprio(0);
    __builtin_amdgcn_s_barrier();

    // ---- phase 2: A m4-7 ; stage Blo(t+2) ----
#pragma unroll
    for (int m = 0; m < 4; ++m) { aq[m][0] = RD(a0 + (m + 4) * 2048); aq[m][1] = RD(a1 + (m + 4) * 2048); }
    if (t + 2 < NKT) STAGE(Bb, LDS_B, t + 2, 0, co);
    __builtin_amdgcn_s_barrier();
    asm volatile("s_waitcnt lgkmcnt(0)");
    __builtin_amdgcn_s_setprio(1);
#pragma unroll
    for (int m = 0; m < 4; ++m)
#pragma unroll
      for (int n = 0; n < 2; ++n)
#pragma unroll
        for (int ks = 0; ks < 2; ++ks)
          acc[m + 4][n] = __builtin_amdgcn_mfma_f32_16x16x32_bf16(aq[m][ks], bl[n][ks], acc[m + 4][n], 0, 0, 0);
    __builtin_amdgcn_s_setprio(0);
    __builtin_amdgcn_s_barrier();

    // ---- phase 3: stage Alo(t+2) ; tile-end counted wait ----
    if (t + 2 < NKT) STAGE(Ab, LDS_A, t + 2, 0, co);
    __builtin_amdgcn_s_barrier();
    __builtin_amdgcn_s_setprio(1);
#pragma unroll
    for (int m = 0; m < 4; ++m)
#pragma unroll
      for (int n = 0; n < 2; ++n)
#pragma unroll
        for (int ks = 0; ks < 2; ++ks)
          acc[m + 4][n + 2] = __builtin_amdgcn_mfma_f32_16x16x32_bf16(aq[m][ks], bh[n][ks], acc[m + 4][n + 2], 0, 0, 0);
    __builtin_amdgcn_s_setprio(0);
    if (t < NKT - 1) {
      if (t + 2 < NKT) asm volatile("s_waitcnt vmcnt(4)");
      else             asm volatile("s_waitcnt vmcnt(0)");
    }
    __builtin_amdgcn_s_barrier();
  }

  // epilogue: C/D layout col=lane&15, row=(lane>>4)*4+reg; temporal stores
  const int colB = tn * 256 + wn * 64 + r16;
  const int rowB = tm * 256 + wm * 128 + kg * 4;
  float bvv[4];
#pragma unroll
  for (int n = 0; n < 4; ++n) bvv[n] = bias[colB + n * 16];
#pragma unroll
  for (int m = 0; m < 8; ++m) {
#pragma unroll
    for (int r = 0; r < 4; ++r) {
      float* cp = C + (size_t)(rowB + m * 16 + r) * DM + colB;
#pragma unroll
      for (int n = 0; n < 4; ++n) cp[n * 16] = acc[m][n][r] + bvv[n];
    }
  }
}

extern "C" void kernel_launch(void* const* d_in, const int* in_sizes, int n_in,
                              void* d_out, int out_size, void* d_ws, size_t ws_size,
                              hipStream_t stream) {
  const float* h = (const float*)d_in[0];
  const float* pat = (const float*)d_in[1];
  const float* w = (const float*)d_in[2];
  const float* b = (const float*)d_in[3];
  float* out = (float*)d_out;
  const int M = in_sizes[0] / DM;  // 65536

  u16* Wb = (u16*)d_ws;                     // 2 MiB
  u16* Abf = (u16*)d_ws + (size_t)DM * DM;  // 128 MiB

  k0_cvt_w<<<DM * DM / 4 / 256, 256, 0, stream>>>(w, Wb);
  k1_hopfield<<<2048, 256, 0, stream>>>(h, pat, Abf, M);
  k2_gemm<<<(M / 256) * (DM / 256), 512, 0, stream>>>(Abf, Wb, b, out, M);
}